// Round 18
// baseline (39598.337 us; speedup 1.0000x reference)
//
#include <hip/hip_runtime.h>
#include <hip/hip_bf16.h>

#define L_SEQ 2048
#define HDIM 512
#define NGATE4 2048   // 4*HD
#define TAGS 48
#define START_TAG 46
#define STOP_TAG 47
#define NWG 32        // workgroups per direction in lstm_layer
#define JPW 16        // h-indices owned per WG

typedef float f32x4 __attribute__((ext_vector_type(4)));

// ---------------------------------------------------------------------------
// GEMM: C[M,N] = A[M,K] @ B[N,K]^T + bias1[n] (+ bias2[n])
// ---------------------------------------------------------------------------
#define BM 64
#define BN 64
#define BK 32
#define LDT 68   // padded LDS row stride (floats)

__global__ __launch_bounds__(256, 2)
void gemm_abt(const float* __restrict__ A, const float* __restrict__ B,
              const float* __restrict__ bias1, const float* __restrict__ bias2,
              float* __restrict__ C, int M, int N, int K,
              const int* __restrict__ gather)
{
  __shared__ float As[BK][LDT];
  __shared__ float Bs[BK][LDT];
  const int tid = threadIdx.x;
  const int m0 = blockIdx.x * BM;
  const int n0 = blockIdx.y * BN;
  const int tm = tid >> 4, tn = tid & 15;
  const int lr = tid >> 2, lk = (tid & 3) * 8;

  float acc[4][4];
#pragma unroll
  for (int i = 0; i < 4; ++i)
#pragma unroll
    for (int c = 0; c < 4; ++c) acc[i][c] = 0.f;

  const int am = m0 + lr;
  const float* arow = gather ? (A + (size_t)gather[am] * (size_t)K)
                             : (A + (size_t)am * (size_t)K);
  const int bn = n0 + lr;
  const float* brow = B + (size_t)bn * (size_t)K;
  const bool bok = (bn < N);

  for (int kt = 0; kt < K; kt += BK) {
    const float4 a0 = *(const float4*)(arow + kt + lk);
    const float4 a1 = *(const float4*)(arow + kt + lk + 4);
    float4 b0 = make_float4(0.f, 0.f, 0.f, 0.f);
    float4 b1 = make_float4(0.f, 0.f, 0.f, 0.f);
    if (bok) {
      b0 = *(const float4*)(brow + kt + lk);
      b1 = *(const float4*)(brow + kt + lk + 4);
    }
    As[lk + 0][lr] = a0.x; As[lk + 1][lr] = a0.y; As[lk + 2][lr] = a0.z; As[lk + 3][lr] = a0.w;
    As[lk + 4][lr] = a1.x; As[lk + 5][lr] = a1.y; As[lk + 6][lr] = a1.z; As[lk + 7][lr] = a1.w;
    Bs[lk + 0][lr] = b0.x; Bs[lk + 1][lr] = b0.y; Bs[lk + 2][lr] = b0.z; Bs[lk + 3][lr] = b0.w;
    Bs[lk + 4][lr] = b1.x; Bs[lk + 5][lr] = b1.y; Bs[lk + 6][lr] = b1.z; Bs[lk + 7][lr] = b1.w;
    __syncthreads();
#pragma unroll
    for (int kk = 0; kk < BK; ++kk) {
      const float4 av = *(const float4*)&As[kk][tm * 4];
      const float4 bv = *(const float4*)&Bs[kk][tn * 4];
      const float aa[4] = {av.x, av.y, av.z, av.w};
      const float bb[4] = {bv.x, bv.y, bv.z, bv.w};
#pragma unroll
      for (int i = 0; i < 4; ++i)
#pragma unroll
        for (int c = 0; c < 4; ++c)
          acc[i][c] += aa[i] * bb[c];
    }
    __syncthreads();
  }

  float bsum[4];
#pragma unroll
  for (int c = 0; c < 4; ++c) {
    const int n = n0 + tn * 4 + c;
    float bb = 0.f;
    if (n < N) { bb = bias1[n]; if (bias2) bb += bias2[n]; }
    bsum[c] = bb;
  }
#pragma unroll
  for (int i = 0; i < 4; ++i) {
    const int m = m0 + tm * 4 + i;
#pragma unroll
    for (int c = 0; c < 4; ++c) {
      const int n = n0 + tn * 4 + c;
      if (n < N) C[(size_t)m * N + n] = acc[i][c] + bsum[c];
    }
  }
}

// ---------------------------------------------------------------------------
// Persistent bidirectional LSTM layer — flag-gated burst exchange,
// minimum waiting-phase traffic. (r16 design; third submission, two infra
// flakes in between — kernel never reached the container either time.)
// r10's FETCH (60MB << 524MB one-hop minimum) shows polls are serviced at
// L3 (the coherence point), so the 3.4µs/step cannot be raw RTT. The
// un-falsified cause is POLL FLOODING: 16K+ concurrent atomic loads/step
// occupy the coherence point and producer stores queue BEHIND the polls
// waiting for them. Fix: waiting phase = wave0's 32 lanes polling 32
// per-producer flags (32 loads/iter/WG, 16x less than r10); payload is
// written once (8B/wave-leader) and burst-read once by wave0 (8 loads/lane)
// after the acquire-flag, then LDS-broadcast. Waves 1-7 wait at the
// barrier, silent. 2-slot ring + layer-unique tags (proven safe); producer
// payload->flag ordering via barrier's vmcnt drain + release flag store.
// Exact f32 throughout. XCD pin kept (neutral, free).
// ---------------------------------------------------------------------------
__global__ __launch_bounds__(512, 1)
void lstm_layer(const float* __restrict__ pre_f, const float* __restrict__ pre_r,
                const float* __restrict__ whh_f, const float* __restrict__ whh_r,
                const float* __restrict__ h0, const float* __restrict__ c0,
                int hcrow_base,
                float* __restrict__ hs_out,    // [L][1024] f32 (next GEMM)
                float* __restrict__ xpay,      // [2 slot][2 dir][512] f32
                int* __restrict__ xflag)       // [2 slot][2 dir][32]
{
  const int sel = blockIdx.x & 7;
  if (sel > 1) return;                      // XCD pin: dir d on XCD d
  const int dir = sel;
  const int wg  = blockIdx.x >> 3;          // 0..31
  const float* pre = dir ? pre_r : pre_f;
  const float* whh = dir ? whh_r : whh_f;
  const int tid = threadIdx.x;
  const int lane = tid & 63;
  const int wave = tid >> 6;                // 0..7
  const int q = lane & 15;                  // k-chunk (32 k)
  const int g = lane >> 4;                  // gate 0..3
  const int j0 = wg * JPW + wave * 2;       // this wave's two h indices
  const int hc = (hcrow_base + dir) * HDIM;
  const unsigned base = (unsigned)((hcrow_base >> 1) * 2048); // 0 | 2048

  __shared__ f32x4 wlds[8][2][8][64];       // [wave][jj][i][lane] = 128 KB
  __shared__ float h_lds[HDIM];

  // Stage weights lane-major; k-window rotated by q (h reads 2-way max, free).
#pragma unroll
  for (int jj = 0; jj < 2; ++jj) {
    const float* wr = whh + (size_t)(g * HDIM + j0 + jj) * HDIM + 32 * q;
#pragma unroll
    for (int i = 0; i < 8; ++i)
      wlds[wave][jj][i][lane] = *(const f32x4*)(wr + 4 * ((i + q) & 7));
  }
  h_lds[tid] = h0[hc + tid];
  float cA = 0.f, cB = 0.f;
  if (lane == 0) { cA = c0[hc + j0]; cB = c0[hc + j0 + 1]; }
  __syncthreads();

  // pre-activation prefetch at gate-leader lanes (q == 0)
  float pa = 0.f, pb = 0.f;
  if (q == 0) {
    const int t0 = dir ? (L_SEQ - 1) : 0;
    const float* pr = pre + (size_t)t0 * NGATE4 + g * HDIM + j0;
    pa = pr[0]; pb = pr[1];
  }

  for (int s = 0; s < L_SEQ; ++s) {
    const int t = dir ? (L_SEQ - 1 - s) : s;
    float pna = 0.f, pnb = 0.f;
    if (q == 0 && (s + 1 < L_SEQ)) {
      const int tnx = dir ? (L_SEQ - 2 - s) : (s + 1);
      const float* pr = pre + (size_t)tnx * NGATE4 + g * HDIM + j0;
      pna = pr[0]; pnb = pr[1];
    }

    f32x4 accA = {0.f, 0.f, 0.f, 0.f};
    f32x4 accB = {0.f, 0.f, 0.f, 0.f};
#pragma unroll
    for (int i = 0; i < 8; ++i) {
      const f32x4 hv = *(const f32x4*)&h_lds[32 * q + 4 * ((i + q) & 7)];
      accA += wlds[wave][0][i][lane] * hv;
      accB += wlds[wave][1][i][lane] * hv;
    }
    float aA = accA.x + accA.y + accA.z + accA.w;
    float aB = accB.x + accB.y + accB.z + accB.w;
#pragma unroll
    for (int m = 1; m < 16; m <<= 1) {     // reduce over q (lane bits 0-3)
      aA += __shfl_xor(aA, m, 64);
      aB += __shfl_xor(aB, m, 64);
    }
    aA += pa; aB += pb;                    // valid at q==0 lanes

    const float fA = __shfl(aA, 16, 64), gA = __shfl(aA, 32, 64), oA = __shfl(aA, 48, 64);
    const float fB = __shfl(aB, 16, 64), gB = __shfl(aB, 32, 64), oB = __shfl(aB, 48, 64);

    if (lane == 0) {
      float hA, hB;
      {
        const float si = 1.f / (1.f + __expf(-aA));
        const float sf = 1.f / (1.f + __expf(-fA));
        const float tg = 1.f - 2.f / (__expf(2.f * gA) + 1.f);
        const float so = 1.f / (1.f + __expf(-oA));
        cA = sf * cA + si * tg;
        hA = so * (1.f - 2.f / (__expf(2.f * cA) + 1.f));
      }
      {
        const float si = 1.f / (1.f + __expf(-aB));
        const float sf = 1.f / (1.f + __expf(-fB));
        const float tg = 1.f - 2.f / (__expf(2.f * gB) + 1.f);
        const float so = 1.f / (1.f + __expf(-oB));
        cB = sf * cB + si * tg;
        hB = so * (1.f - 2.f / (__expf(2.f * cB) + 1.f));
      }
      // payload: one 8B relaxed agent store (both j's) into the ring slot
      const unsigned long long pw =
          (unsigned long long)__float_as_uint(hA)
          | ((unsigned long long)__float_as_uint(hB) << 32);
      __hip_atomic_store(
          (unsigned long long*)&xpay[((s + 1) & 1) * 1024 + dir * HDIM + j0],
          pw, __ATOMIC_RELAXED, __HIP_MEMORY_SCOPE_AGENT);
      // hs_out for the later GEMM (visible after kernel-end flush)
      float2 hv2; hv2.x = hA; hv2.y = hB;
      *(float2*)&hs_out[(size_t)t * 1024 + dir * HDIM + j0] = hv2;
    }
    pa = pna; pb = pnb;

    if (s == L_SEQ - 1) break;

    __syncthreads();   // drains ALL waves' payload stores (vmcnt0 @ barrier)

    if (wave == 0) {
      const int expect = (int)(base + (unsigned)s + 1u);
      int* fbase = xflag + ((s + 1) & 1) * 64 + dir * 32;
      if (tid == 0)      // publish: payload already drained by the barrier
        __hip_atomic_store(&fbase[wg], expect, __ATOMIC_RELEASE,
                           __HIP_MEMORY_SCOPE_AGENT);
      // waiting phase: 32 lanes x 32 flags only (no payload traffic)
      for (;;) {
        const int v = (lane < NWG)
            ? __hip_atomic_load(&fbase[lane], __ATOMIC_ACQUIRE,
                                __HIP_MEMORY_SCOPE_AGENT)
            : expect;
        if (__all(v == expect)) break;
      }
      // burst: wave0 alone reads the 512-float payload once and broadcasts
      const float* pp = xpay + ((s + 1) & 1) * 1024 + dir * HDIM;
      float hv[8];
#pragma unroll
      for (int b = 0; b < 8; ++b)
        hv[b] = __hip_atomic_load(pp + lane + b * 64, __ATOMIC_RELAXED,
                                  __HIP_MEMORY_SCOPE_AGENT);
#pragma unroll
      for (int b = 0; b < 8; ++b)
        h_lds[lane + b * 64] = hv[b];
    }
    __syncthreads();                       // h_lds[s+1] fully written
  }
}

// ---------------------------------------------------------------------------
// Viterbi: 1 WG, 192 threads = (48 tags) x (4 k-chunks of 12).
// ---------------------------------------------------------------------------
__global__ __launch_bounds__(192, 1)
void viterbi_kernel(const float* __restrict__ feats,
                    const float* __restrict__ trans,
                    int* __restrict__ bp,      // [L][48]
                    float* __restrict__ out)   // [1 + L]
{
  __shared__ float fv[TAGS];
  __shared__ float fvn[TAGS];
  const int tid = threadIdx.x;
  const int lane = tid & 63;
  const int wave = tid >> 6;
  const int q = lane & 3;
  const int j = wave * 16 + (lane >> 2);  // 0..47

  float trr[12];
#pragma unroll
  for (int kk = 0; kk < 12; ++kk) trr[kk] = trans[j * TAGS + q * 12 + kk];

  if (tid < TAGS) fv[tid] = (tid == START_TAG) ? 0.f : -10000.f;
  __syncthreads();

  for (int t = 0; t < L_SEQ; ++t) {
    const float ft = feats[t * TAGS + j];
    float best = -3.0e38f;
    int bi = 0;
#pragma unroll
    for (int kk = 0; kk < 12; ++kk) {
      const int k = q * 12 + kk;
      const float sc = fv[k] + trr[kk];
      if (sc > best) { best = sc; bi = k; }   // strict > keeps first max
    }
#pragma unroll
    for (int m = 1; m < 4; m <<= 1) {
      const float ov = __shfl_xor(best, m, 64);
      const int oi = __shfl_xor(bi, m, 64);
      if (ov > best || (ov == best && oi < bi)) { best = ov; bi = oi; }
    }
    __syncthreads();
    if (q == 0) {
      bp[t * TAGS + j] = bi;
      fv[j] = best + ft;
    }
    __syncthreads();
  }

  if (tid < TAGS) fvn[tid] = fv[tid] + trans[STOP_TAG * TAGS + tid];
  __syncthreads();
  if (tid == 0) {
    float best = -3.0e38f;
    int bi = 0;
    for (int k = 0; k < TAGS; ++k) {
      const float v = fvn[k];
      if (v > best) { best = v; bi = k; }
    }
    out[0] = best;
    int cur = bi;
    out[1 + (L_SEQ - 1)] = (float)cur;
    for (int t = L_SEQ - 2; t >= 0; --t) {
      cur = bp[(t + 1) * TAGS + cur];
      out[1 + t] = (float)cur;
    }
  }
}

// ---------------------------------------------------------------------------
extern "C" void kernel_launch(void* const* d_in, const int* in_sizes, int n_in,
                              void* d_out, int out_size, void* d_ws, size_t ws_size,
                              hipStream_t stream)
{
  const int*   sentence  = (const int*)  d_in[0];
  const float* embedding = (const float*)d_in[1];
  const float* w_ih_l0   = (const float*)d_in[2];
  const float* w_hh_l0   = (const float*)d_in[3];
  const float* b_ih_l0   = (const float*)d_in[4];
  const float* b_hh_l0   = (const float*)d_in[5];
  const float* w_ih_l0r  = (const float*)d_in[6];
  const float* w_hh_l0r  = (const float*)d_in[7];
  const float* b_ih_l0r  = (const float*)d_in[8];
  const float* b_hh_l0r  = (const float*)d_in[9];
  const float* w_ih_l1   = (const float*)d_in[10];
  const float* w_hh_l1   = (const float*)d_in[11];
  const float* b_ih_l1   = (const float*)d_in[12];
  const float* b_hh_l1   = (const float*)d_in[13];
  const float* w_ih_l1r  = (const float*)d_in[14];
  const float* w_hh_l1r  = (const float*)d_in[15];
  const float* b_ih_l1r  = (const float*)d_in[16];
  const float* b_hh_l1r  = (const float*)d_in[17];
  const float* h0        = (const float*)d_in[18];
  const float* c0        = (const float*)d_in[19];
  const float* W_tag     = (const float*)d_in[20];
  const float* b_tag     = (const float*)d_in[21];
  const float* trans     = (const float*)d_in[22];

  float* ws    = (float*)d_ws;
  float* pre_f = ws;                                  // [L][2048]
  float* pre_r = pre_f + (size_t)L_SEQ * NGATE4;      // [L][2048]
  float* l0out = pre_r + (size_t)L_SEQ * NGATE4;      // [L][1024]
  float* l1out = l0out + (size_t)L_SEQ * 1024;        // [L][1024]
  float* feats = l1out + (size_t)L_SEQ * 1024;        // [L][48]
  float* xpay  = feats + (size_t)L_SEQ * TAGS;        // [2][2][512] f32
  int*   xflag = (int*)(xpay + 2048);                 // [2][2][32]
  int*   bp    = xflag + 128;                         // [L][48]

  (void)hipMemsetAsync(xpay, 0, 2048 * sizeof(float) + 128 * sizeof(int),
                       stream);

  dim3 blk(256);
  dim3 gfull(L_SEQ / BM, NGATE4 / BN);
  gemm_abt<<<gfull, blk, 0, stream>>>(embedding, w_ih_l0, b_ih_l0, b_hh_l0,
                                      pre_f, L_SEQ, NGATE4, 512, sentence);
  gemm_abt<<<gfull, blk, 0, stream>>>(embedding, w_ih_l0r, b_ih_l0r, b_hh_l0r,
                                      pre_r, L_SEQ, NGATE4, 512, sentence);
  lstm_layer<<<256, 512, 0, stream>>>(pre_f, pre_r, w_hh_l0, w_hh_l0r,
                                      h0, c0, 0, l0out, xpay, xflag);
  gemm_abt<<<gfull, blk, 0, stream>>>(l0out, w_ih_l1, b_ih_l1, b_hh_l1,
                                      pre_f, L_SEQ, NGATE4, 1024, nullptr);
  gemm_abt<<<gfull, blk, 0, stream>>>(l0out, w_ih_l1r, b_ih_l1r, b_hh_l1r,
                                      pre_r, L_SEQ, NGATE4, 1024, nullptr);
  lstm_layer<<<256, 512, 0, stream>>>(pre_f, pre_r, w_hh_l1, w_hh_l1r,
                                      h0, c0, 2, l1out, xpay, xflag);
  dim3 gfeat(L_SEQ / BM, 1);
  gemm_abt<<<gfeat, blk, 0, stream>>>(l1out, W_tag, b_tag, nullptr,
                                      feats, L_SEQ, TAGS, 1024, nullptr);
  viterbi_kernel<<<1, 192, 0, stream>>>(feats, trans, bp, (float*)d_out);
}

// Round 19
// 15415.182 us; speedup vs baseline: 2.5688x; 2.5688x over previous
//
#include <hip/hip_runtime.h>
#include <hip/hip_bf16.h>

#define L_SEQ 2048
#define HDIM 512
#define NGATE4 2048   // 4*HD
#define TAGS 48
#define START_TAG 46
#define STOP_TAG 47
#define NWG 32        // workgroups per direction in lstm_layer
#define JPW 16        // h-indices owned per WG

typedef float f32x4 __attribute__((ext_vector_type(4)));

// ---------------------------------------------------------------------------
// GEMM: C[M,N] = A[M,K] @ B[N,K]^T + bias1[n] (+ bias2[n])
// ---------------------------------------------------------------------------
#define BM 64
#define BN 64
#define BK 32
#define LDT 68   // padded LDS row stride (floats)

__global__ __launch_bounds__(256, 2)
void gemm_abt(const float* __restrict__ A, const float* __restrict__ B,
              const float* __restrict__ bias1, const float* __restrict__ bias2,
              float* __restrict__ C, int M, int N, int K,
              const int* __restrict__ gather)
{
  __shared__ float As[BK][LDT];
  __shared__ float Bs[BK][LDT];
  const int tid = threadIdx.x;
  const int m0 = blockIdx.x * BM;
  const int n0 = blockIdx.y * BN;
  const int tm = tid >> 4, tn = tid & 15;
  const int lr = tid >> 2, lk = (tid & 3) * 8;

  float acc[4][4];
#pragma unroll
  for (int i = 0; i < 4; ++i)
#pragma unroll
    for (int c = 0; c < 4; ++c) acc[i][c] = 0.f;

  const int am = m0 + lr;
  const float* arow = gather ? (A + (size_t)gather[am] * (size_t)K)
                             : (A + (size_t)am * (size_t)K);
  const int bn = n0 + lr;
  const float* brow = B + (size_t)bn * (size_t)K;
  const bool bok = (bn < N);

  for (int kt = 0; kt < K; kt += BK) {
    const float4 a0 = *(const float4*)(arow + kt + lk);
    const float4 a1 = *(const float4*)(arow + kt + lk + 4);
    float4 b0 = make_float4(0.f, 0.f, 0.f, 0.f);
    float4 b1 = make_float4(0.f, 0.f, 0.f, 0.f);
    if (bok) {
      b0 = *(const float4*)(brow + kt + lk);
      b1 = *(const float4*)(brow + kt + lk + 4);
    }
    As[lk + 0][lr] = a0.x; As[lk + 1][lr] = a0.y; As[lk + 2][lr] = a0.z; As[lk + 3][lr] = a0.w;
    As[lk + 4][lr] = a1.x; As[lk + 5][lr] = a1.y; As[lk + 6][lr] = a1.z; As[lk + 7][lr] = a1.w;
    Bs[lk + 0][lr] = b0.x; Bs[lk + 1][lr] = b0.y; Bs[lk + 2][lr] = b0.z; Bs[lk + 3][lr] = b0.w;
    Bs[lk + 4][lr] = b1.x; Bs[lk + 5][lr] = b1.y; Bs[lk + 6][lr] = b1.z; Bs[lk + 7][lr] = b1.w;
    __syncthreads();
#pragma unroll
    for (int kk = 0; kk < BK; ++kk) {
      const float4 av = *(const float4*)&As[kk][tm * 4];
      const float4 bv = *(const float4*)&Bs[kk][tn * 4];
      const float aa[4] = {av.x, av.y, av.z, av.w};
      const float bb[4] = {bv.x, bv.y, bv.z, bv.w};
#pragma unroll
      for (int i = 0; i < 4; ++i)
#pragma unroll
        for (int c = 0; c < 4; ++c)
          acc[i][c] += aa[i] * bb[c];
    }
    __syncthreads();
  }

  float bsum[4];
#pragma unroll
  for (int c = 0; c < 4; ++c) {
    const int n = n0 + tn * 4 + c;
    float bb = 0.f;
    if (n < N) { bb = bias1[n]; if (bias2) bb += bias2[n]; }
    bsum[c] = bb;
  }
#pragma unroll
  for (int i = 0; i < 4; ++i) {
    const int m = m0 + tm * 4 + i;
#pragma unroll
    for (int c = 0; c < 4; ++c) {
      const int n = n0 + tn * 4 + c;
      if (n < N) C[(size_t)m * N + n] = acc[i][c] + bsum[c];
    }
  }
}

// ---------------------------------------------------------------------------
// Persistent bidirectional LSTM layer — r10 protocol restored (best known:
// 7.0ms/layer, exact f32), + s_sleep poll throttle.
// Final picture from r3-r18: ONE-HOP exchange (data rides the poll word) is
// 3.4µs/step; every two-hop variant (slots r7, flag+burst r16) is 5.6-8.5;
// the 3.4 is invariant to protocol/participants/placement/sharing/traffic
// -> device coherence-point RTT floor. This kernel: 32 WGs x 512 thr/dir,
// weights f32 in 128KB LDS (lane-major, conflict-free), exchange =
// 64-bit (f32 h | 32-bit layer-unique tag) relaxed agent word, 2-slot ring,
// every consumer polls its OWN word; s_sleep(1) (~64cy) between polls cuts
// issue pressure ~10x at -27ns wake cost. XCD pin kept (neutral, free).
// ---------------------------------------------------------------------------
__global__ __launch_bounds__(512, 1)
void lstm_layer(const float* __restrict__ pre_f, const float* __restrict__ pre_r,
                const float* __restrict__ whh_f, const float* __restrict__ whh_r,
                const float* __restrict__ h0, const float* __restrict__ c0,
                int hcrow_base,
                float* __restrict__ hs_out,    // [L][1024] f32 (next GEMM)
                unsigned long long* __restrict__ xch) // [2 slot][2 dir][512]
{
  const int sel = blockIdx.x & 7;
  if (sel > 1) return;                      // XCD pin: dir d on XCD d
  const int dir = sel;
  const int wg  = blockIdx.x >> 3;          // 0..31
  const float* pre = dir ? pre_r : pre_f;
  const float* whh = dir ? whh_r : whh_f;
  const int tid = threadIdx.x;
  const int lane = tid & 63;
  const int wave = tid >> 6;                // 0..7
  const int q = lane & 15;                  // k-chunk (32 k)
  const int g = lane >> 4;                  // gate 0..3
  const int j0 = wg * JPW + wave * 2;       // this wave's two h indices
  const int hc = (hcrow_base + dir) * HDIM;
  const unsigned base = (unsigned)((hcrow_base >> 1) * 2048); // 0 | 2048

  __shared__ f32x4 wlds[8][2][8][64];       // [wave][jj][i][lane] = 128 KB
  __shared__ float h_lds[HDIM];

  // Stage weights lane-major; k-window rotated by q (h reads 2-way max, free).
#pragma unroll
  for (int jj = 0; jj < 2; ++jj) {
    const float* wr = whh + (size_t)(g * HDIM + j0 + jj) * HDIM + 32 * q;
#pragma unroll
    for (int i = 0; i < 8; ++i)
      wlds[wave][jj][i][lane] = *(const f32x4*)(wr + 4 * ((i + q) & 7));
  }
  h_lds[tid] = h0[hc + tid];
  float cA = 0.f, cB = 0.f;
  if (lane == 0) { cA = c0[hc + j0]; cB = c0[hc + j0 + 1]; }
  __syncthreads();

  // pre-activation prefetch at gate-leader lanes (q == 0)
  float pa = 0.f, pb = 0.f;
  if (q == 0) {
    const int t0 = dir ? (L_SEQ - 1) : 0;
    const float* pr = pre + (size_t)t0 * NGATE4 + g * HDIM + j0;
    pa = pr[0]; pb = pr[1];
  }

  for (int s = 0; s < L_SEQ; ++s) {
    const int t = dir ? (L_SEQ - 1 - s) : s;
    float pna = 0.f, pnb = 0.f;
    if (q == 0 && (s + 1 < L_SEQ)) {
      const int tnx = dir ? (L_SEQ - 2 - s) : (s + 1);
      const float* pr = pre + (size_t)tnx * NGATE4 + g * HDIM + j0;
      pna = pr[0]; pnb = pr[1];
    }

    f32x4 accA = {0.f, 0.f, 0.f, 0.f};
    f32x4 accB = {0.f, 0.f, 0.f, 0.f};
#pragma unroll
    for (int i = 0; i < 8; ++i) {
      const f32x4 hv = *(const f32x4*)&h_lds[32 * q + 4 * ((i + q) & 7)];
      accA += wlds[wave][0][i][lane] * hv;
      accB += wlds[wave][1][i][lane] * hv;
    }
    float aA = accA.x + accA.y + accA.z + accA.w;
    float aB = accB.x + accB.y + accB.z + accB.w;
#pragma unroll
    for (int m = 1; m < 16; m <<= 1) {     // reduce over q (lane bits 0-3)
      aA += __shfl_xor(aA, m, 64);
      aB += __shfl_xor(aB, m, 64);
    }
    aA += pa; aB += pb;                    // valid at q==0 lanes

    const float fA = __shfl(aA, 16, 64), gA = __shfl(aA, 32, 64), oA = __shfl(aA, 48, 64);
    const float fB = __shfl(aB, 16, 64), gB = __shfl(aB, 32, 64), oB = __shfl(aB, 48, 64);

    if (lane == 0) {
      const unsigned long long tag = (unsigned long long)(base + (unsigned)s + 1u);
      const size_t wb = ((size_t)((s + 1) & 1) * 2 + dir) * 512 + j0;
      float hA, hB;
      {
        const float si = 1.f / (1.f + __expf(-aA));
        const float sf = 1.f / (1.f + __expf(-fA));
        const float tg = 1.f - 2.f / (__expf(2.f * gA) + 1.f);
        const float so = 1.f / (1.f + __expf(-oA));
        cA = sf * cA + si * tg;
        hA = so * (1.f - 2.f / (__expf(2.f * cA) + 1.f));
      }
      {
        const float si = 1.f / (1.f + __expf(-aB));
        const float sf = 1.f / (1.f + __expf(-fB));
        const float tg = 1.f - 2.f / (__expf(2.f * gB) + 1.f);
        const float so = 1.f / (1.f + __expf(-oB));
        cB = sf * cB + si * tg;
        hB = so * (1.f - 2.f / (__expf(2.f * cB) + 1.f));
      }
      const unsigned long long wA =
          ((unsigned long long)__float_as_uint(hA) << 32) | tag;
      const unsigned long long wB =
          ((unsigned long long)__float_as_uint(hB) << 32) | tag;
      __hip_atomic_store(xch + wb, wA, __ATOMIC_RELAXED, __HIP_MEMORY_SCOPE_AGENT);
      __hip_atomic_store(xch + wb + 1, wB, __ATOMIC_RELAXED, __HIP_MEMORY_SCOPE_AGENT);
      float2 hv2; hv2.x = hA; hv2.y = hB;
      *(float2*)&hs_out[(size_t)t * 1024 + dir * HDIM + j0] = hv2;
    }
    pa = pna; pb = pnb;

    if (s == L_SEQ - 1) break;

    __syncthreads();                       // all lanes done reading h_lds[s]
    {
      const unsigned expect = base + (unsigned)s + 1u;
      const unsigned long long* wp =
          xch + ((size_t)((s + 1) & 1) * 2 + dir) * 512 + tid;
      unsigned long long v;
      for (;;) {
        v = __hip_atomic_load(wp, __ATOMIC_RELAXED, __HIP_MEMORY_SCOPE_AGENT);
        if ((unsigned)v == expect) break;
        __builtin_amdgcn_s_sleep(1);       // ~64cy pause: cut poll pressure
      }
      h_lds[tid] = __uint_as_float((unsigned)(v >> 32));
    }
    __syncthreads();                       // h_lds[s+1] fully written
  }
}

// ---------------------------------------------------------------------------
// Viterbi: 1 WG, 192 threads = (48 tags) x (4 k-chunks of 12).
// ---------------------------------------------------------------------------
__global__ __launch_bounds__(192, 1)
void viterbi_kernel(const float* __restrict__ feats,
                    const float* __restrict__ trans,
                    int* __restrict__ bp,      // [L][48]
                    float* __restrict__ out)   // [1 + L]
{
  __shared__ float fv[TAGS];
  __shared__ float fvn[TAGS];
  const int tid = threadIdx.x;
  const int lane = tid & 63;
  const int wave = tid >> 6;
  const int q = lane & 3;
  const int j = wave * 16 + (lane >> 2);  // 0..47

  float trr[12];
#pragma unroll
  for (int kk = 0; kk < 12; ++kk) trr[kk] = trans[j * TAGS + q * 12 + kk];

  if (tid < TAGS) fv[tid] = (tid == START_TAG) ? 0.f : -10000.f;
  __syncthreads();

  for (int t = 0; t < L_SEQ; ++t) {
    const float ft = feats[t * TAGS + j];
    float best = -3.0e38f;
    int bi = 0;
#pragma unroll
    for (int kk = 0; kk < 12; ++kk) {
      const int k = q * 12 + kk;
      const float sc = fv[k] + trr[kk];
      if (sc > best) { best = sc; bi = k; }   // strict > keeps first max
    }
#pragma unroll
    for (int m = 1; m < 4; m <<= 1) {
      const float ov = __shfl_xor(best, m, 64);
      const int oi = __shfl_xor(bi, m, 64);
      if (ov > best || (ov == best && oi < bi)) { best = ov; bi = oi; }
    }
    __syncthreads();
    if (q == 0) {
      bp[t * TAGS + j] = bi;
      fv[j] = best + ft;
    }
    __syncthreads();
  }

  if (tid < TAGS) fvn[tid] = fv[tid] + trans[STOP_TAG * TAGS + tid];
  __syncthreads();
  if (tid == 0) {
    float best = -3.0e38f;
    int bi = 0;
    for (int k = 0; k < TAGS; ++k) {
      const float v = fvn[k];
      if (v > best) { best = v; bi = k; }
    }
    out[0] = best;
    int cur = bi;
    out[1 + (L_SEQ - 1)] = (float)cur;
    for (int t = L_SEQ - 2; t >= 0; --t) {
      cur = bp[(t + 1) * TAGS + cur];
      out[1 + t] = (float)cur;
    }
  }
}

// ---------------------------------------------------------------------------
extern "C" void kernel_launch(void* const* d_in, const int* in_sizes, int n_in,
                              void* d_out, int out_size, void* d_ws, size_t ws_size,
                              hipStream_t stream)
{
  const int*   sentence  = (const int*)  d_in[0];
  const float* embedding = (const float*)d_in[1];
  const float* w_ih_l0   = (const float*)d_in[2];
  const float* w_hh_l0   = (const float*)d_in[3];
  const float* b_ih_l0   = (const float*)d_in[4];
  const float* b_hh_l0   = (const float*)d_in[5];
  const float* w_ih_l0r  = (const float*)d_in[6];
  const float* w_hh_l0r  = (const float*)d_in[7];
  const float* b_ih_l0r  = (const float*)d_in[8];
  const float* b_hh_l0r  = (const float*)d_in[9];
  const float* w_ih_l1   = (const float*)d_in[10];
  const float* w_hh_l1   = (const float*)d_in[11];
  const float* b_ih_l1   = (const float*)d_in[12];
  const float* b_hh_l1   = (const float*)d_in[13];
  const float* w_ih_l1r  = (const float*)d_in[14];
  const float* w_hh_l1r  = (const float*)d_in[15];
  const float* b_ih_l1r  = (const float*)d_in[16];
  const float* b_hh_l1r  = (const float*)d_in[17];
  const float* h0        = (const float*)d_in[18];
  const float* c0        = (const float*)d_in[19];
  const float* W_tag     = (const float*)d_in[20];
  const float* b_tag     = (const float*)d_in[21];
  const float* trans     = (const float*)d_in[22];

  float* ws    = (float*)d_ws;
  float* pre_f = ws;                                  // [L][2048]
  float* pre_r = pre_f + (size_t)L_SEQ * NGATE4;      // [L][2048]
  float* l0out = pre_r + (size_t)L_SEQ * NGATE4;      // [L][1024]
  float* l1out = l0out + (size_t)L_SEQ * 1024;        // [L][1024]
  float* feats = l1out + (size_t)L_SEQ * 1024;        // [L][48]
  unsigned long long* xch =
      (unsigned long long*)(feats + (size_t)L_SEQ * TAGS); // [2][2][512] u64
  int*   bp    = (int*)(xch + 2048);                  // [L][48]

  (void)hipMemsetAsync(xch, 0, 2048 * sizeof(unsigned long long), stream);

  dim3 blk(256);
  dim3 gfull(L_SEQ / BM, NGATE4 / BN);
  gemm_abt<<<gfull, blk, 0, stream>>>(embedding, w_ih_l0, b_ih_l0, b_hh_l0,
                                      pre_f, L_SEQ, NGATE4, 512, sentence);
  gemm_abt<<<gfull, blk, 0, stream>>>(embedding, w_ih_l0r, b_ih_l0r, b_hh_l0r,
                                      pre_r, L_SEQ, NGATE4, 512, sentence);
  lstm_layer<<<256, 512, 0, stream>>>(pre_f, pre_r, w_hh_l0, w_hh_l0r,
                                      h0, c0, 0, l0out, xch);
  gemm_abt<<<gfull, blk, 0, stream>>>(l0out, w_ih_l1, b_ih_l1, b_hh_l1,
                                      pre_f, L_SEQ, NGATE4, 1024, nullptr);
  gemm_abt<<<gfull, blk, 0, stream>>>(l0out, w_ih_l1r, b_ih_l1r, b_hh_l1r,
                                      pre_r, L_SEQ, NGATE4, 1024, nullptr);
  lstm_layer<<<256, 512, 0, stream>>>(pre_f, pre_r, w_hh_l1, w_hh_l1r,
                                      h0, c0, 2, l1out, xch);
  dim3 gfeat(L_SEQ / BM, 1);
  gemm_abt<<<gfeat, blk, 0, stream>>>(l1out, W_tag, b_tag, nullptr,
                                      feats, L_SEQ, TAGS, 1024, nullptr);
  viterbi_kernel<<<1, 192, 0, stream>>>(feats, trans, bp, (float*)d_out);
}